// Round 11
// baseline (329.387 us; speedup 1.0000x reference)
//
#include <hip/hip_runtime.h>
#include <hip/hip_bf16.h>

#define NB 262144
#define RTILE 64

typedef __bf16 bf16x8 __attribute__((ext_vector_type(8)));
typedef float f32x4 __attribute__((ext_vector_type(4)));

// ---- packed bf16 weight buffer ----
// MFMA layers fragment-ordered: fragment (colTile,ks) at
//   off + ((colTile*KSTRIDE + ks)*64 + lane)*8
// lane's elems: W[col=colTile*16+(lane&15)][k=ks*32+(lane>>4)*8+e].
// Wsig/Wrgb plain row-major.
#define OFF_W0   0        // [256][64]   (K 63->64)
#define OFF_W1   16384    // [256][256]
#define OFF_W2   81920
#define OFF_W3   147456
#define OFF_W4   212992
#define OFF_W5   278528   // [256][320]  (K 319->320; ks 8,9 = x)
#define OFF_W6   360448
#define OFF_W7   425984
#define OFF_WSIG 491520   // [1][256] plain
#define OFF_W8   491776   // [256][256]
#define OFF_W9   557312   // [128][288]  (K 283->288; ks 8 = d)
#define OFF_W10  594176   // [128][128]
#define OFF_W11  610560
#define OFF_W12  626944
#define OFF_WRGB 643328   // [3][128] plain
#define WTOTAL   643712

__device__ __align__(16) unsigned short g_w[WTOTAL];

__device__ __forceinline__ unsigned short f2bfu(float f) {
  __bf16 h = (__bf16)f;
  return __builtin_bit_cast(unsigned short, h);
}
__device__ __forceinline__ float bfu2f(unsigned short u) {
  return (float)__builtin_bit_cast(__bf16, u);
}

__global__ void prep_kernel(const float* W0, const float* W1, const float* W2,
                            const float* W3, const float* W4, const float* W5,
                            const float* W6, const float* W7, const float* Wsig,
                            const float* W8, const float* W9, const float* W10,
                            const float* W11, const float* W12, const float* Wrgb) {
  const float* srcs[15] = {W0,W1,W2,W3,W4,W5,W6,W7,Wsig,W8,W9,W10,W11,W12,Wrgb};
  const int dsto[16] = {OFF_W0,OFF_W1,OFF_W2,OFF_W3,OFF_W4,OFF_W5,OFF_W6,OFF_W7,
                        OFF_WSIG,OFF_W8,OFF_W9,OFF_W10,OFF_W11,OFF_W12,OFF_WRGB,WTOTAL};
  const int kpad[15] = {64,256,256,256,256,320,256,256,256,256,288,128,128,128,128};
  const int ksrc[15] = {63,256,256,256,256,319,256,256,256,256,283,128,128,128,128};
  int idx = blockIdx.x * blockDim.x + threadIdx.x;
  if (idx >= WTOTAL) return;
  int r = 0;
  for (int i = 1; i < 15; ++i) if (idx >= dsto[i]) r = i;
  int local = idx - dsto[r];
  float v;
  if (r == 8 || r == 14) {             // head weights: plain row-major
    int o = local / kpad[r];
    int k = local - o * kpad[r];
    v = (k < ksrc[r]) ? srcs[r][o * ksrc[r] + k] : 0.0f;
  } else {                             // MFMA layers: fragment-ordered
    const int KS = kpad[r] >> 5;
    int frag = local >> 9;
    int within = local & 511;
    int lane = within >> 3;
    int e = within & 7;
    int colTile = frag / KS;
    int ks = frag - colTile * KS;
    int col = colTile * 16 + (lane & 15);
    int k = ks * 32 + (lane >> 4) * 8 + e;
    v = (k < ksrc[r]) ? srcs[r][col * ksrc[r] + k] : 0.0f;
  }
  g_w[idx] = f2bfu(v);
}

// ---- fused MLP ----
// Round-10 structure + round-11 changes:
// (1) H is CHUNK-ROTATED: element (r,c) lives at column
//     hcol = ((((c>>5)+(r&7))&7)<<5) | (c&31)   (pad cols 256..263 untouched)
//     Row stride 264 elems = 132 dwords == 4 (mod 32): without rotation every
//     b128 A-read had 8 lanes per 4-bank group (the constant ~3.4e7 conflict
//     counter). Rotation spreads the 8 chunk-classes across all banks -> ~2-way.
//     ALL H writers (store_acc*) and readers (gemm A1, ROT=true) use it.
// (2) bias folded into accumulator init (C-in of first MFMA) -> no bias add
//     in the store epilogue.
// Swapped-operand MFMA: acc = mfma(W_frag, H_frag) -> lane holds
// row rt*16+l15, cols ct*16+l4*4+0..3.
template<int KS1, int KS2, int KSTRIDE, int NT, bool ROT1>
__device__ __forceinline__ void gemm_compute(
    const unsigned short* A1, int sA1,
    const unsigned short* A2, int sA2,
    const unsigned short* Wp,
    const float* bias,                  // folded into acc init
    f32x4 (&acc)[4][NT],
    int lane, int wid)
{
  const int l15 = lane & 15;
  const int l4  = lane >> 4;
  const int sx  = l15 & 7;
  const unsigned short* wb = Wp + (size_t)(wid * NT) * KSTRIDE * 512 + lane * 8;

  // init acc with bias (each lane: cols ct*16+l4*4+0..3, all row-tiles)
#pragma unroll
  for (int ct = 0; ct < NT; ++ct) {
    const f32x4 bv = *(const f32x4*)&bias[wid * (NT * 16) + ct * 16 + l4 * 4];
#pragma unroll
    for (int rt = 0; rt < 4; ++rt)
      acc[rt][ct] = bv;
  }

#pragma unroll
  for (int kk = 0; kk < KS1 + KS2; ++kk) {
    bf16x8 a[4];
    if (kk < KS1) {
      const int koff = ROT1 ? ((((kk + sx) & 7) << 5) + l4 * 8)
                            : (kk * 32 + l4 * 8);
#pragma unroll
      for (int rt = 0; rt < 4; ++rt)
        a[rt] = *(const bf16x8*)&A1[(rt * 16 + l15) * sA1 + koff];
    } else {
      const int koff = (kk - KS1) * 32 + l4 * 8;
#pragma unroll
      for (int rt = 0; rt < 4; ++rt)
        a[rt] = *(const bf16x8*)&A2[(rt * 16 + l15) * sA2 + koff];
    }
    bf16x8 b[NT];
#pragma unroll
    for (int ct = 0; ct < NT; ++ct)
      b[ct] = *(const bf16x8*)&wb[(size_t)(ct * KSTRIDE + kk) * 512];
    // swapped operands: W-frag in the A slot, H-frag in the B slot
#pragma unroll
    for (int ct = 0; ct < NT; ++ct)
#pragma unroll
      for (int rt = 0; rt < 4; ++rt)
        acc[rt][ct] = __builtin_amdgcn_mfma_f32_16x16x32_bf16(b[ct], a[rt], acc[rt][ct], 0, 0, 0);
  }
}

// Store to rotated H. acc already contains bias.
template<int NT, bool RELU>
__device__ __forceinline__ void store_acc(
    const f32x4 (&acc)[4][NT],
    unsigned short* Out, int sO, int lane, int wid)
{
  const int l15 = lane & 15;
  const int l4  = lane >> 4;
  const int sx  = l15 & 7;
  const int colbase = wid * (NT * 16);
#pragma unroll
  for (int ct = 0; ct < NT; ++ct) {
    const int col0 = colbase + ct * 16 + l4 * 4;
    const int pcol0 = ((((col0 >> 5) + sx) & 7) << 5) | (col0 & 31);
#pragma unroll
    for (int rt = 0; rt < 4; ++rt) {
      const int row = rt * 16 + l15;
      float v0 = acc[rt][ct][0];
      float v1 = acc[rt][ct][1];
      float v2 = acc[rt][ct][2];
      float v3 = acc[rt][ct][3];
      if (RELU) {
        v0 = fmaxf(v0, 0.f); v1 = fmaxf(v1, 0.f);
        v2 = fmaxf(v2, 0.f); v3 = fmaxf(v3, 0.f);
      }
      uint2 u;
      u.x = (unsigned)f2bfu(v0) | ((unsigned)f2bfu(v1) << 16);
      u.y = (unsigned)f2bfu(v2) | ((unsigned)f2bfu(v3) << 16);
      *(uint2*)&Out[row * sO + pcol0] = u;
    }
  }
}

// L7 store + sigma partial dot (h7 . Wsig) fused; rotated write, acc has bias.
__device__ __forceinline__ void store_acc_sigma(
    const f32x4 (&acc)[4][4],
    unsigned short* Out, int sO, float* Sb, int lane, int wid)
{
  const int l15 = lane & 15;
  const int l4  = lane >> 4;
  const int sx  = l15 & 7;
  const int colbase = wid * 64;
  float ps[4] = {0.f, 0.f, 0.f, 0.f};
#pragma unroll
  for (int ct = 0; ct < 4; ++ct) {
    const int col0 = colbase + ct * 16 + l4 * 4;
    const int pcol0 = ((((col0 >> 5) + sx) & 7) << 5) | (col0 & 31);
    const ushort4 wu = *(const ushort4*)&g_w[OFF_WSIG + col0];
    const float w0 = bfu2f(wu.x), w1 = bfu2f(wu.y), w2 = bfu2f(wu.z), w3 = bfu2f(wu.w);
#pragma unroll
    for (int rt = 0; rt < 4; ++rt) {
      const int row = rt * 16 + l15;
      float v0 = fmaxf(acc[rt][ct][0], 0.f);
      float v1 = fmaxf(acc[rt][ct][1], 0.f);
      float v2 = fmaxf(acc[rt][ct][2], 0.f);
      float v3 = fmaxf(acc[rt][ct][3], 0.f);
      uint2 u;
      u.x = (unsigned)f2bfu(v0) | ((unsigned)f2bfu(v1) << 16);
      u.y = (unsigned)f2bfu(v2) | ((unsigned)f2bfu(v3) << 16);
      *(uint2*)&Out[row * sO + pcol0] = u;
      ps[rt] += bfu2f(f2bfu(v0)) * w0 + bfu2f(f2bfu(v1)) * w1
              + bfu2f(f2bfu(v2)) * w2 + bfu2f(f2bfu(v3)) * w3;
    }
  }
#pragma unroll
  for (int rt = 0; rt < 4; ++rt) {
    ps[rt] += __shfl_xor(ps[rt], 16);
    ps[rt] += __shfl_xor(ps[rt], 32);
  }
  if (l4 == 0) {
#pragma unroll
    for (int rt = 0; rt < 4; ++rt)
      Sb[wid * 64 + rt * 16 + l15] = ps[rt];
  }
}

// L12 epilogue: rgb partials straight from acc2 (acc already has bias).
__device__ __forceinline__ void rgb_partial(
    const f32x4 (&acc)[4][2],
    float* Rb, int lane, int wid)
{
  const int l15 = lane & 15;
  const int l4  = lane >> 4;
  const int colbase = wid * 32;
  float pr[4][3] = {};
#pragma unroll
  for (int ct = 0; ct < 2; ++ct) {
    const int col0 = colbase + ct * 16 + l4 * 4;
    float wf[3][4];
#pragma unroll
    for (int ch = 0; ch < 3; ++ch) {
      const ushort4 wu = *(const ushort4*)&g_w[OFF_WRGB + ch * 128 + col0];
      wf[ch][0] = bfu2f(wu.x); wf[ch][1] = bfu2f(wu.y);
      wf[ch][2] = bfu2f(wu.z); wf[ch][3] = bfu2f(wu.w);
    }
#pragma unroll
    for (int rt = 0; rt < 4; ++rt) {
      float v0 = fmaxf(acc[rt][ct][0], 0.f);
      float v1 = fmaxf(acc[rt][ct][1], 0.f);
      float v2 = fmaxf(acc[rt][ct][2], 0.f);
      float v3 = fmaxf(acc[rt][ct][3], 0.f);
#pragma unroll
      for (int ch = 0; ch < 3; ++ch)
        pr[rt][ch] += v0 * wf[ch][0] + v1 * wf[ch][1] + v2 * wf[ch][2] + v3 * wf[ch][3];
    }
  }
#pragma unroll
  for (int rt = 0; rt < 4; ++rt)
#pragma unroll
    for (int ch = 0; ch < 3; ++ch) {
      pr[rt][ch] += __shfl_xor(pr[rt][ch], 16);
      pr[rt][ch] += __shfl_xor(pr[rt][ch], 32);
    }
  if (l4 == 0) {
#pragma unroll
    for (int rt = 0; rt < 4; ++rt)
#pragma unroll
      for (int ch = 0; ch < 3; ++ch)
        Rb[((wid * 4 + rt) * 3 + ch) * 16 + l15] = pr[rt][ch];
  }
}

__launch_bounds__(256, 3)
__global__ void nerf_main(const float* __restrict__ x, const float* __restrict__ d,
    const float* b0, const float* b1, const float* b2, const float* b3,
    const float* b4, const float* b5, const float* b6, const float* b7,
    const float* bsig, const float* b8, const float* b9, const float* b10,
    const float* b11, const float* b12, const float* brgb,
    float* __restrict__ out)
{
  __shared__ unsigned short H[64 * 264];   // 33792 B, chunk-rotated
  __shared__ unsigned short Xb[64 * 72];   // 9216 B, plain; col 63 zeroed
  __shared__ unsigned short Db[64 * 40];   // 5120 B, plain; cols 27..31 zeroed
  __shared__ float Sb[256];                // 1024 B sigma partials
  __shared__ float Rb[768];                // 3072 B rgb partials
  // total 52224 B -> 3 blocks/CU

  const int tid = threadIdx.x;
  const int lane = tid & 63;
  const int wid = tid >> 6;
  const int rowbase = blockIdx.x * RTILE;

  // ---- stage x and d tiles (fp32 -> bf16, plain layout) ----
  {
    const int r = tid >> 2;      // 0..63
    const int sub = tid & 3;
    const float* xr = x + (size_t)(rowbase + r) * 63;
    for (int j = 0; j < 16; ++j) {
      const int c = sub + j * 4;        // 0..63
      Xb[r * 72 + c] = (c < 63) ? f2bfu(xr[c]) : (unsigned short)0;
    }
    const float* dr = d + (size_t)(rowbase + r) * 27;
    for (int j = 0; j < 8; ++j) {
      const int c = sub + j * 4;        // 0..31
      Db[r * 40 + c] = (c < 27) ? f2bfu(dr[c]) : (unsigned short)0;
    }
  }
  __syncthreads();

  f32x4 acc4[4][4];
  f32x4 acc2[4][2];

  // L0: reads Xb (plain) -> write H (rotated)
  gemm_compute<2,0,2,4,false>(Xb, 72, nullptr, 0, g_w + OFF_W0, b0, acc4, lane, wid);
  store_acc<4,true>(acc4, H, 264, lane, wid);
  __syncthreads();

#define BIG_LAYER(OFFW, BIAS) \
  gemm_compute<8,0,8,4,true>(H, 264, nullptr, 0, g_w + OFFW, BIAS, acc4, lane, wid); \
  __syncthreads(); \
  store_acc<4,true>(acc4, H, 264, lane, wid); \
  __syncthreads();

  BIG_LAYER(OFF_W1, b1)
  BIG_LAYER(OFF_W2, b2)
  BIG_LAYER(OFF_W3, b3)
  BIG_LAYER(OFF_W4, b4)

  // L5: concat [h(256) rotated | x(63)+pad plain] -> K=320
  gemm_compute<8,2,10,4,true>(H, 264, Xb, 72, g_w + OFF_W5, b5, acc4, lane, wid);
  __syncthreads();
  store_acc<4,true>(acc4, H, 264, lane, wid);
  __syncthreads();

  BIG_LAYER(OFF_W6, b6)

  // L7 + fused sigma partials
  gemm_compute<8,0,8,4,true>(H, 264, nullptr, 0, g_w + OFF_W7, b7, acc4, lane, wid);
  __syncthreads();
  store_acc_sigma(acc4, H, 264, Sb, lane, wid);
  __syncthreads();

  // finish sigma: 64 threads
  if (tid < 64) {
    float s = Sb[tid] + Sb[64 + tid] + Sb[128 + tid] + Sb[192 + tid] + bsig[0];
    float sp = (s > 0.f) ? (s + log1pf(expf(-s))) : log1pf(expf(s));
    out[3 * NB + rowbase + tid] = sp;
  }

  // L8 (bottleneck, no relu)
  gemm_compute<8,0,8,4,true>(H, 264, nullptr, 0, g_w + OFF_W8, b8, acc4, lane, wid);
  __syncthreads();
  store_acc<4,false>(acc4, H, 264, lane, wid);
  __syncthreads();

  // L9: concat [h8(256) rotated | d(27)+pad plain] -> K=288, N=128
  gemm_compute<8,1,9,2,true>(H, 264, Db, 40, g_w + OFF_W9, b9, acc2, lane, wid);
  __syncthreads();
  store_acc<2,true>(acc2, H, 264, lane, wid);
  __syncthreads();

#define SMALL_LAYER(OFFW, BIAS) \
  gemm_compute<4,0,4,2,true>(H, 264, nullptr, 0, g_w + OFFW, BIAS, acc2, lane, wid); \
  __syncthreads(); \
  store_acc<2,true>(acc2, H, 264, lane, wid); \
  __syncthreads();

  SMALL_LAYER(OFF_W10, b10)
  SMALL_LAYER(OFF_W11, b11)

  // L12 + fused rgb head: h12 never touches LDS
  gemm_compute<4,0,4,2,true>(H, 264, nullptr, 0, g_w + OFF_W12, b12, acc2, lane, wid);
  rgb_partial(acc2, Rb, lane, wid);
  __syncthreads();

  if (tid < 192) {
    const int r = tid / 3;
    const int ch = tid - r * 3;
    const int rt = r >> 4;
    const int l15r = r & 15;
    float s = brgb[ch];
#pragma unroll
    for (int w = 0; w < 4; ++w)
      s += Rb[((w * 4 + rt) * 3 + ch) * 16 + l15r];
    float val = 1.f / (1.f + expf(-s));
    out[(size_t)(rowbase + r) * 3 + ch] = val;
  }
}

extern "C" void kernel_launch(void* const* d_in, const int* in_sizes, int n_in,
                              void* d_out, int out_size, void* d_ws, size_t ws_size,
                              hipStream_t stream) {
  const float* x    = (const float*)d_in[0];
  const float* dd   = (const float*)d_in[1];
  const float* W0   = (const float*)d_in[2];
  const float* b0   = (const float*)d_in[3];
  const float* W1   = (const float*)d_in[4];
  const float* b1   = (const float*)d_in[5];
  const float* W2   = (const float*)d_in[6];
  const float* b2   = (const float*)d_in[7];
  const float* W3   = (const float*)d_in[8];
  const float* b3   = (const float*)d_in[9];
  const float* W4   = (const float*)d_in[10];
  const float* b4   = (const float*)d_in[11];
  const float* W5   = (const float*)d_in[12];
  const float* b5   = (const float*)d_in[13];
  const float* W6   = (const float*)d_in[14];
  const float* b6   = (const float*)d_in[15];
  const float* W7   = (const float*)d_in[16];
  const float* b7   = (const float*)d_in[17];
  const float* Wsig = (const float*)d_in[18];
  const float* bsig = (const float*)d_in[19];
  const float* W8   = (const float*)d_in[20];
  const float* b8   = (const float*)d_in[21];
  const float* W9   = (const float*)d_in[22];
  const float* b9   = (const float*)d_in[23];
  const float* W10  = (const float*)d_in[24];
  const float* b10  = (const float*)d_in[25];
  const float* W11  = (const float*)d_in[26];
  const float* b11  = (const float*)d_in[27];
  const float* W12  = (const float*)d_in[28];
  const float* b12  = (const float*)d_in[29];
  const float* Wrgb = (const float*)d_in[30];
  const float* brgb = (const float*)d_in[31];

  prep_kernel<<<(WTOTAL + 255) / 256, 256, 0, stream>>>(
      W0, W1, W2, W3, W4, W5, W6, W7, Wsig, W8, W9, W10, W11, W12, Wrgb);

  nerf_main<<<NB / RTILE, 256, 0, stream>>>(
      x, dd, b0, b1, b2, b3, b4, b5, b6, b7, bsig, b8, b9, b10, b11, b12, brgb,
      (float*)d_out);
}

// Round 12
// 314.277 us; speedup vs baseline: 1.0481x; 1.0481x over previous
//
#include <hip/hip_runtime.h>
#include <hip/hip_bf16.h>

#define NB 262144
#define RTILE 64

typedef __bf16 bf16x8 __attribute__((ext_vector_type(8)));
typedef float f32x4 __attribute__((ext_vector_type(4)));

// ---- packed bf16 weight buffer ----
// MFMA layers fragment-ordered: fragment (colTile,ks) at
//   off + ((colTile*KSTRIDE + ks)*64 + lane)*8
// lane's elems: W[col=colTile*16+(lane&15)][k=ks*32+(lane>>4)*8+e].
// Wsig/Wrgb plain row-major.
#define OFF_W0   0        // [256][64]   (K 63->64)
#define OFF_W1   16384    // [256][256]
#define OFF_W2   81920
#define OFF_W3   147456
#define OFF_W4   212992
#define OFF_W5   278528   // [256][320]  (K 319->320; ks 8,9 = x)
#define OFF_W6   360448
#define OFF_W7   425984
#define OFF_WSIG 491520   // [1][256] plain
#define OFF_W8   491776   // [256][256]
#define OFF_W9   557312   // [128][288]  (K 283->288; ks 8 = d)
#define OFF_W10  594176   // [128][128]
#define OFF_W11  610560
#define OFF_W12  626944
#define OFF_WRGB 643328   // [3][128] plain
#define WTOTAL   643712

__device__ __align__(16) unsigned short g_w[WTOTAL];

__device__ __forceinline__ unsigned short f2bfu(float f) {
  __bf16 h = (__bf16)f;
  return __builtin_bit_cast(unsigned short, h);
}
__device__ __forceinline__ float bfu2f(unsigned short u) {
  return (float)__builtin_bit_cast(__bf16, u);
}

__global__ void prep_kernel(const float* W0, const float* W1, const float* W2,
                            const float* W3, const float* W4, const float* W5,
                            const float* W6, const float* W7, const float* Wsig,
                            const float* W8, const float* W9, const float* W10,
                            const float* W11, const float* W12, const float* Wrgb) {
  const float* srcs[15] = {W0,W1,W2,W3,W4,W5,W6,W7,Wsig,W8,W9,W10,W11,W12,Wrgb};
  const int dsto[16] = {OFF_W0,OFF_W1,OFF_W2,OFF_W3,OFF_W4,OFF_W5,OFF_W6,OFF_W7,
                        OFF_WSIG,OFF_W8,OFF_W9,OFF_W10,OFF_W11,OFF_W12,OFF_WRGB,WTOTAL};
  const int kpad[15] = {64,256,256,256,256,320,256,256,256,256,288,128,128,128,128};
  const int ksrc[15] = {63,256,256,256,256,319,256,256,256,256,283,128,128,128,128};
  int idx = blockIdx.x * blockDim.x + threadIdx.x;
  if (idx >= WTOTAL) return;
  int r = 0;
  for (int i = 1; i < 15; ++i) if (idx >= dsto[i]) r = i;
  int local = idx - dsto[r];
  float v;
  if (r == 8 || r == 14) {             // head weights: plain row-major
    int o = local / kpad[r];
    int k = local - o * kpad[r];
    v = (k < ksrc[r]) ? srcs[r][o * ksrc[r] + k] : 0.0f;
  } else {                             // MFMA layers: fragment-ordered
    const int KS = kpad[r] >> 5;
    int frag = local >> 9;
    int within = local & 511;
    int lane = within >> 3;
    int e = within & 7;
    int colTile = frag / KS;
    int ks = frag - colTile * KS;
    int col = colTile * 16 + (lane & 15);
    int k = ks * 32 + (lane >> 4) * 8 + e;
    v = (k < ksrc[r]) ? srcs[r][col * ksrc[r] + k] : 0.0f;
  }
  g_w[idx] = f2bfu(v);
}

// ---- fused MLP ----
// Round-12: activations H (and Xb, Db) stored in LDS in MFMA-FRAGMENT ORDER,
// identical to the weight layout: element (row, c) of a 64-row tile lives at
//   (rt*KSH + (c>>5))*512 + lane*8 + e,  rt=row>>4, lane=(row&15)+16*((c>>3)&3), e=c&7
// KSH = 8 for H (256 cols), 2 for Xb, 1 for Db. A-reads in the K-loop become
//   base + (rt*KSH + kk)*512 + lane*8   -- lane-linear b128, conflict-free,
// address = SGPR base + immediate (same as weight loads). This removes the
// per-kstep VALU address arithmetic AND the structural A-read bank conflicts
// of the row-major layout (stride 132 dwords == 4 mod 32).
// Swapped-operand MFMA (r9): acc = mfma(W_frag, H_frag) -> lane holds
// row rt*16+l15, cols ct*16+l4*4+0..3; store = one b64 per (rt,ct).
template<int KS1, int KSA1, int KS2, int KSA2, int KSTRIDE, int NT>
__device__ __forceinline__ void gemm_compute(
    const unsigned short* A1,
    const unsigned short* A2,
    const unsigned short* Wp,
    f32x4 (&acc)[4][NT],
    int lane, int wid)
{
  const unsigned short* wb = Wp + (size_t)(wid * NT) * KSTRIDE * 512 + lane * 8;
  const unsigned short* a1 = A1 + lane * 8;
  const unsigned short* a2 = A2 ? (A2 + lane * 8) : nullptr;

#pragma unroll
  for (int rt = 0; rt < 4; ++rt)
#pragma unroll
    for (int ct = 0; ct < NT; ++ct)
      acc[rt][ct] = (f32x4){0.f, 0.f, 0.f, 0.f};

#pragma unroll
  for (int kk = 0; kk < KS1 + KS2; ++kk) {
    bf16x8 a[4];
    if (kk < KS1) {
#pragma unroll
      for (int rt = 0; rt < 4; ++rt)
        a[rt] = *(const bf16x8*)&a1[(rt * KSA1 + kk) * 512];
    } else {
#pragma unroll
      for (int rt = 0; rt < 4; ++rt)
        a[rt] = *(const bf16x8*)&a2[(rt * KSA2 + (kk - KS1)) * 512];
    }
    bf16x8 b[NT];
#pragma unroll
    for (int ct = 0; ct < NT; ++ct)
      b[ct] = *(const bf16x8*)&wb[(size_t)(ct * KSTRIDE + kk) * 512];
    // swapped operands: W-frag in the A slot, H-frag in the B slot
#pragma unroll
    for (int ct = 0; ct < NT; ++ct)
#pragma unroll
      for (int rt = 0; rt < 4; ++rt)
        acc[rt][ct] = __builtin_amdgcn_mfma_f32_16x16x32_bf16(b[ct], a[rt], acc[rt][ct], 0, 0, 0);
  }
}

// Store acc (+bias, relu) into fragment-ordered H (KSH=8 stride).
template<int NT, bool RELU>
__device__ __forceinline__ void store_acc(
    const f32x4 (&acc)[4][NT], const float* bias,
    unsigned short* Out, int lane, int wid)
{
  const int l15 = lane & 15;
  const int l4  = lane >> 4;
  const int colbase = wid * (NT * 16);
#pragma unroll
  for (int ct = 0; ct < NT; ++ct) {
    const int c0 = colbase + ct * 16 + l4 * 4;
    const f32x4 bv = *(const f32x4*)&bias[c0];
    const int f  = c0 >> 5;
    const int li = l15 + 16 * ((c0 >> 3) & 3);
    const int e0 = c0 & 7;
#pragma unroll
    for (int rt = 0; rt < 4; ++rt) {
      float v0 = acc[rt][ct][0] + bv[0];
      float v1 = acc[rt][ct][1] + bv[1];
      float v2 = acc[rt][ct][2] + bv[2];
      float v3 = acc[rt][ct][3] + bv[3];
      if (RELU) {
        v0 = fmaxf(v0, 0.f); v1 = fmaxf(v1, 0.f);
        v2 = fmaxf(v2, 0.f); v3 = fmaxf(v3, 0.f);
      }
      uint2 u;
      u.x = (unsigned)f2bfu(v0) | ((unsigned)f2bfu(v1) << 16);
      u.y = (unsigned)f2bfu(v2) | ((unsigned)f2bfu(v3) << 16);
      *(uint2*)&Out[(rt * 8 + f) * 512 + li * 8 + e0] = u;
    }
  }
}

// L7 store + fused sigma partials (h7 . Wsig); fragment-ordered write.
__device__ __forceinline__ void store_acc_sigma(
    const f32x4 (&acc)[4][4], const float* bias,
    unsigned short* Out, float* Sb, int lane, int wid)
{
  const int l15 = lane & 15;
  const int l4  = lane >> 4;
  const int colbase = wid * 64;
  float ps[4] = {0.f, 0.f, 0.f, 0.f};
#pragma unroll
  for (int ct = 0; ct < 4; ++ct) {
    const int c0 = colbase + ct * 16 + l4 * 4;
    const f32x4 bv = *(const f32x4*)&bias[c0];
    const int f  = c0 >> 5;
    const int li = l15 + 16 * ((c0 >> 3) & 3);
    const int e0 = c0 & 7;
    const ushort4 wu = *(const ushort4*)&g_w[OFF_WSIG + c0];
    const float w0 = bfu2f(wu.x), w1 = bfu2f(wu.y), w2 = bfu2f(wu.z), w3 = bfu2f(wu.w);
#pragma unroll
    for (int rt = 0; rt < 4; ++rt) {
      float v0 = fmaxf(acc[rt][ct][0] + bv[0], 0.f);
      float v1 = fmaxf(acc[rt][ct][1] + bv[1], 0.f);
      float v2 = fmaxf(acc[rt][ct][2] + bv[2], 0.f);
      float v3 = fmaxf(acc[rt][ct][3] + bv[3], 0.f);
      uint2 u;
      u.x = (unsigned)f2bfu(v0) | ((unsigned)f2bfu(v1) << 16);
      u.y = (unsigned)f2bfu(v2) | ((unsigned)f2bfu(v3) << 16);
      *(uint2*)&Out[(rt * 8 + f) * 512 + li * 8 + e0] = u;
      ps[rt] += bfu2f(f2bfu(v0)) * w0 + bfu2f(f2bfu(v1)) * w1
              + bfu2f(f2bfu(v2)) * w2 + bfu2f(f2bfu(v3)) * w3;
    }
  }
#pragma unroll
  for (int rt = 0; rt < 4; ++rt) {
    ps[rt] += __shfl_xor(ps[rt], 16);
    ps[rt] += __shfl_xor(ps[rt], 32);
  }
  if (l4 == 0) {
#pragma unroll
    for (int rt = 0; rt < 4; ++rt)
      Sb[wid * 64 + rt * 16 + l15] = ps[rt];
  }
}

// L12 epilogue: rgb partials straight from acc2.
__device__ __forceinline__ void rgb_partial(
    const f32x4 (&acc)[4][2], const float* bias,
    float* Rb, int lane, int wid)
{
  const int l15 = lane & 15;
  const int l4  = lane >> 4;
  const int colbase = wid * 32;
  float pr[4][3] = {};
#pragma unroll
  for (int ct = 0; ct < 2; ++ct) {
    const int c0 = colbase + ct * 16 + l4 * 4;
    const f32x4 bv = *(const f32x4*)&bias[c0];
    float wf[3][4];
#pragma unroll
    for (int ch = 0; ch < 3; ++ch) {
      const ushort4 wu = *(const ushort4*)&g_w[OFF_WRGB + ch * 128 + c0];
      wf[ch][0] = bfu2f(wu.x); wf[ch][1] = bfu2f(wu.y);
      wf[ch][2] = bfu2f(wu.z); wf[ch][3] = bfu2f(wu.w);
    }
#pragma unroll
    for (int rt = 0; rt < 4; ++rt) {
      float v0 = fmaxf(acc[rt][ct][0] + bv[0], 0.f);
      float v1 = fmaxf(acc[rt][ct][1] + bv[1], 0.f);
      float v2 = fmaxf(acc[rt][ct][2] + bv[2], 0.f);
      float v3 = fmaxf(acc[rt][ct][3] + bv[3], 0.f);
#pragma unroll
      for (int ch = 0; ch < 3; ++ch)
        pr[rt][ch] += v0 * wf[ch][0] + v1 * wf[ch][1] + v2 * wf[ch][2] + v3 * wf[ch][3];
    }
  }
#pragma unroll
  for (int rt = 0; rt < 4; ++rt)
#pragma unroll
    for (int ch = 0; ch < 3; ++ch) {
      pr[rt][ch] += __shfl_xor(pr[rt][ch], 16);
      pr[rt][ch] += __shfl_xor(pr[rt][ch], 32);
    }
  if (l4 == 0) {
#pragma unroll
    for (int rt = 0; rt < 4; ++rt)
#pragma unroll
      for (int ch = 0; ch < 3; ++ch)
        Rb[((wid * 4 + rt) * 3 + ch) * 16 + l15] = pr[rt][ch];
  }
}

__launch_bounds__(256, 3)
__global__ void nerf_main(const float* __restrict__ x, const float* __restrict__ d,
    const float* b0, const float* b1, const float* b2, const float* b3,
    const float* b4, const float* b5, const float* b6, const float* b7,
    const float* bsig, const float* b8, const float* b9, const float* b10,
    const float* b11, const float* b12, const float* brgb,
    float* __restrict__ out)
{
  __shared__ __align__(16) unsigned short H[64 * 256];   // 32768 B, fragment-ordered KSH=8
  __shared__ __align__(16) unsigned short Xb[64 * 64];   // 8192 B, fragment-ordered KSX=2
  __shared__ __align__(16) unsigned short Db[64 * 32];   // 4096 B, fragment-ordered KSD=1
  __shared__ float Sb[256];                // 1024 B sigma partials
  __shared__ float Rb[768];                // 3072 B rgb partials
  // total 49152 B -> 3 blocks/CU

  const int tid = threadIdx.x;
  const int lane = tid & 63;
  const int wid = tid >> 6;
  const int rowbase = blockIdx.x * RTILE;

  // ---- stage x and d tiles (fp32 -> bf16, fragment-ordered writes) ----
  {
    const int r = tid >> 2;      // 0..63
    const int sub = tid & 3;
    const int rt = r >> 4;
    const int rl = r & 15;
    const float* xr = x + (size_t)(rowbase + r) * 63;
    for (int j = 0; j < 16; ++j) {
      const int c = sub + j * 4;        // 0..63
      const unsigned short v = (c < 63) ? f2bfu(xr[c]) : (unsigned short)0;
      Xb[(rt * 2 + (c >> 5)) * 512 + (rl + 16 * ((c >> 3) & 3)) * 8 + (c & 7)] = v;
    }
    const float* dr = d + (size_t)(rowbase + r) * 27;
    for (int j = 0; j < 8; ++j) {
      const int c = sub + j * 4;        // 0..31
      const unsigned short v = (c < 27) ? f2bfu(dr[c]) : (unsigned short)0;
      Db[rt * 512 + (rl + 16 * ((c >> 3) & 3)) * 8 + (c & 7)] = v;
    }
  }
  __syncthreads();

  f32x4 acc4[4][4];
  f32x4 acc2[4][2];

  // L0: reads Xb only -> write H directly (first writer)
  gemm_compute<2,2,0,0,2,4>(Xb, nullptr, g_w + OFF_W0, acc4, lane, wid);
  store_acc<4,true>(acc4, b0, H, lane, wid);
  __syncthreads();

#define BIG_LAYER(OFFW, BIAS) \
  gemm_compute<8,8,0,0,8,4>(H, nullptr, g_w + OFFW, acc4, lane, wid); \
  __syncthreads(); \
  store_acc<4,true>(acc4, BIAS, H, lane, wid); \
  __syncthreads();

  BIG_LAYER(OFF_W1, b1)
  BIG_LAYER(OFF_W2, b2)
  BIG_LAYER(OFF_W3, b3)
  BIG_LAYER(OFF_W4, b4)

  // L5: concat [h(256) | x(63)+pad] -> K=320
  gemm_compute<8,8,2,2,10,4>(H, Xb, g_w + OFF_W5, acc4, lane, wid);
  __syncthreads();
  store_acc<4,true>(acc4, b5, H, lane, wid);
  __syncthreads();

  BIG_LAYER(OFF_W6, b6)

  // L7 + fused sigma partials
  gemm_compute<8,8,0,0,8,4>(H, nullptr, g_w + OFF_W7, acc4, lane, wid);
  __syncthreads();
  store_acc_sigma(acc4, b7, H, Sb, lane, wid);
  __syncthreads();

  // finish sigma: 64 threads, Sb stable from here on
  if (tid < 64) {
    float s = Sb[tid] + Sb[64 + tid] + Sb[128 + tid] + Sb[192 + tid] + bsig[0];
    float sp = (s > 0.f) ? (s + log1pf(expf(-s))) : log1pf(expf(s));
    out[3 * NB + rowbase + tid] = sp;
  }

  // L8 (bottleneck, no relu)
  gemm_compute<8,8,0,0,8,4>(H, nullptr, g_w + OFF_W8, acc4, lane, wid);
  __syncthreads();
  store_acc<4,false>(acc4, b8, H, lane, wid);
  __syncthreads();

  // L9: concat [h8(256) | d(27)+pad] -> K=288, N=128 (d from Db)
  gemm_compute<8,8,1,1,9,2>(H, Db, g_w + OFF_W9, acc2, lane, wid);
  __syncthreads();
  store_acc<2,true>(acc2, b9, H, lane, wid);
  __syncthreads();

#define SMALL_LAYER(OFFW, BIAS) \
  gemm_compute<4,8,0,0,4,2>(H, nullptr, g_w + OFFW, acc2, lane, wid); \
  __syncthreads(); \
  store_acc<2,true>(acc2, BIAS, H, lane, wid); \
  __syncthreads();

  SMALL_LAYER(OFF_W10, b10)
  SMALL_LAYER(OFF_W11, b11)

  // L12 + fused rgb head: h12 never touches LDS
  gemm_compute<4,8,0,0,4,2>(H, nullptr, g_w + OFF_W12, acc2, lane, wid);
  rgb_partial(acc2, b12, Rb, lane, wid);
  __syncthreads();

  if (tid < 192) {
    const int r = tid / 3;
    const int ch = tid - r * 3;
    const int rt = r >> 4;
    const int l15r = r & 15;
    float s = brgb[ch];
#pragma unroll
    for (int w = 0; w < 4; ++w)
      s += Rb[((w * 4 + rt) * 3 + ch) * 16 + l15r];
    float val = 1.f / (1.f + expf(-s));
    out[(size_t)(rowbase + r) * 3 + ch] = val;
  }
}

extern "C" void kernel_launch(void* const* d_in, const int* in_sizes, int n_in,
                              void* d_out, int out_size, void* d_ws, size_t ws_size,
                              hipStream_t stream) {
  const float* x    = (const float*)d_in[0];
  const float* dd   = (const float*)d_in[1];
  const float* W0   = (const float*)d_in[2];
  const float* b0   = (const float*)d_in[3];
  const float* W1   = (const float*)d_in[4];
  const float* b1   = (const float*)d_in[5];
  const float* W2   = (const float*)d_in[6];
  const float* b2   = (const float*)d_in[7];
  const float* W3   = (const float*)d_in[8];
  const float* b3   = (const float*)d_in[9];
  const float* W4   = (const float*)d_in[10];
  const float* b4   = (const float*)d_in[11];
  const float* W5   = (const float*)d_in[12];
  const float* b5   = (const float*)d_in[13];
  const float* W6   = (const float*)d_in[14];
  const float* b6   = (const float*)d_in[15];
  const float* W7   = (const float*)d_in[16];
  const float* b7   = (const float*)d_in[17];
  const float* Wsig = (const float*)d_in[18];
  const float* bsig = (const float*)d_in[19];
  const float* W8   = (const float*)d_in[20];
  const float* b8   = (const float*)d_in[21];
  const float* W9   = (const float*)d_in[22];
  const float* b9   = (const float*)d_in[23];
  const float* W10  = (const float*)d_in[24];
  const float* b10  = (const float*)d_in[25];
  const float* W11  = (const float*)d_in[26];
  const float* b11  = (const float*)d_in[27];
  const float* W12  = (const float*)d_in[28];
  const float* b12  = (const float*)d_in[29];
  const float* Wrgb = (const float*)d_in[30];
  const float* brgb = (const float*)d_in[31];

  prep_kernel<<<(WTOTAL + 255) / 256, 256, 0, stream>>>(
      W0, W1, W2, W3, W4, W5, W6, W7, Wsig, W8, W9, W10, W11, W12, Wrgb);

  nerf_main<<<NB / RTILE, 256, 0, stream>>>(
      x, dd, b0, b1, b2, b3, b4, b5, b6, b7, bsig, b8, b9, b10, b11, b12, brgb,
      (float*)d_out);
}

// Round 13
// 300.412 us; speedup vs baseline: 1.0965x; 1.0462x over previous
//
#include <hip/hip_runtime.h>
#include <hip/hip_bf16.h>

#define NB 262144
#define RTILE 64

typedef __bf16 bf16x8 __attribute__((ext_vector_type(8)));
typedef float f32x4 __attribute__((ext_vector_type(4)));

// ---- packed bf16 weight buffer ----
// MFMA layers fragment-ordered: fragment (colTile,ks) at
//   off + ((colTile*KSTRIDE + ks)*64 + lane)*8
// lane's elems: W[col=colTile*16+(lane&15)][k=ks*32+(lane>>4)*8+e].
// Wsig/Wrgb plain row-major.
#define OFF_W0   0        // [256][64]   (K 63->64)
#define OFF_W1   16384    // [256][256]
#define OFF_W2   81920
#define OFF_W3   147456
#define OFF_W4   212992
#define OFF_W5   278528   // [256][320]  (K 319->320; ks 8,9 = x)
#define OFF_W6   360448
#define OFF_W7   425984
#define OFF_WSIG 491520   // [1][256] plain
#define OFF_W8   491776   // [256][256]
#define OFF_W9   557312   // [128][288]  (K 283->288; ks 8 = d)
#define OFF_W10  594176   // [128][128]
#define OFF_W11  610560
#define OFF_W12  626944
#define OFF_WRGB 643328   // [3][128] plain
#define WTOTAL   643712

__device__ __align__(16) unsigned short g_w[WTOTAL];

__device__ __forceinline__ unsigned short f2bfu(float f) {
  __bf16 h = (__bf16)f;
  return __builtin_bit_cast(unsigned short, h);
}
__device__ __forceinline__ float bfu2f(unsigned short u) {
  return (float)__builtin_bit_cast(__bf16, u);
}

__global__ void prep_kernel(const float* W0, const float* W1, const float* W2,
                            const float* W3, const float* W4, const float* W5,
                            const float* W6, const float* W7, const float* Wsig,
                            const float* W8, const float* W9, const float* W10,
                            const float* W11, const float* W12, const float* Wrgb) {
  const float* srcs[15] = {W0,W1,W2,W3,W4,W5,W6,W7,Wsig,W8,W9,W10,W11,W12,Wrgb};
  const int dsto[16] = {OFF_W0,OFF_W1,OFF_W2,OFF_W3,OFF_W4,OFF_W5,OFF_W6,OFF_W7,
                        OFF_WSIG,OFF_W8,OFF_W9,OFF_W10,OFF_W11,OFF_W12,OFF_WRGB,WTOTAL};
  const int kpad[15] = {64,256,256,256,256,320,256,256,256,256,288,128,128,128,128};
  const int ksrc[15] = {63,256,256,256,256,319,256,256,256,256,283,128,128,128,128};
  int idx = blockIdx.x * blockDim.x + threadIdx.x;
  if (idx >= WTOTAL) return;
  int r = 0;
  for (int i = 1; i < 15; ++i) if (idx >= dsto[i]) r = i;
  int local = idx - dsto[r];
  float v;
  if (r == 8 || r == 14) {             // head weights: plain row-major
    int o = local / kpad[r];
    int k = local - o * kpad[r];
    v = (k < ksrc[r]) ? srcs[r][o * ksrc[r] + k] : 0.0f;
  } else {                             // MFMA layers: fragment-ordered
    const int KS = kpad[r] >> 5;
    int frag = local >> 9;
    int within = local & 511;
    int lane = within >> 3;
    int e = within & 7;
    int colTile = frag / KS;
    int ks = frag - colTile * KS;
    int col = colTile * 16 + (lane & 15);
    int k = ks * 32 + (lane >> 4) * 8 + e;
    v = (k < ksrc[r]) ? srcs[r][col * ksrc[r] + k] : 0.0f;
  }
  g_w[idx] = f2bfu(v);
}

// ---- fused MLP ----
// Round-12 fragment-ordered LDS for H/Xb/Db (lane-linear conflict-free reads,
// SGPR-base+immediate addressing) + round-13 EXPLICIT K-LOOP SOFTWARE PIPELINE:
// the B (weight) fragments come from global/L2 (~200 cyc); with no prefetch
// each kstep serializes to ~280 cyc (load-wait + 16 MFMA). We prefetch
// kstep kk+1's B-frags before kk's MFMAs (bcur/bnxt double buffer, +16 VGPR)
// and rotate each a[rt] (LDS, ~120 cyc) right after its last use in kk.
// s_setprio(1) around the MFMA cluster (independent blocks per CU = the
// regime where setprio measured +4-7%).
// Swapped-operand MFMA (r9): acc = mfma(W_frag, H_frag) -> lane holds
// row rt*16+l15, cols ct*16+l4*4+0..3; store = one b64 per (rt,ct).
template<int KS1, int KSA1, int KS2, int KSA2, int KSTRIDE, int NT>
__device__ __forceinline__ void gemm_compute(
    const unsigned short* A1,
    const unsigned short* A2,
    const unsigned short* Wp,
    f32x4 (&acc)[4][NT],
    int lane, int wid)
{
  constexpr int KS = KS1 + KS2;
  const unsigned short* wb = Wp + (size_t)(wid * NT) * KSTRIDE * 512 + lane * 8;
  const unsigned short* a1 = A1 + lane * 8;
  const unsigned short* a2 = A2 ? (A2 + lane * 8) : nullptr;

#pragma unroll
  for (int rt = 0; rt < 4; ++rt)
#pragma unroll
    for (int ct = 0; ct < NT; ++ct)
      acc[rt][ct] = (f32x4){0.f, 0.f, 0.f, 0.f};

  bf16x8 a[4], bcur[NT], bnxt[NT];
  // preload kstep 0
#pragma unroll
  for (int ct = 0; ct < NT; ++ct)
    bcur[ct] = *(const bf16x8*)&wb[(size_t)(ct * KSTRIDE) * 512];
#pragma unroll
  for (int rt = 0; rt < 4; ++rt)
    a[rt] = *(const bf16x8*)&a1[(rt * KSA1) * 512];

#pragma unroll
  for (int kk = 0; kk < KS; ++kk) {
    // prefetch next kstep's B-frags (global/L2) before this kstep's MFMAs
    if (kk + 1 < KS) {
#pragma unroll
      for (int ct = 0; ct < NT; ++ct)
        bnxt[ct] = *(const bf16x8*)&wb[(size_t)(ct * KSTRIDE + kk + 1) * 512];
    }
    __builtin_amdgcn_s_setprio(1);
#pragma unroll
    for (int rt = 0; rt < 4; ++rt) {
#pragma unroll
      for (int ct = 0; ct < NT; ++ct)
        acc[rt][ct] = __builtin_amdgcn_mfma_f32_16x16x32_bf16(bcur[ct], a[rt], acc[rt][ct], 0, 0, 0);
      // rotate this row-tile's A-frag to kstep kk+1 (LDS latency hides
      // under the remaining row-tiles' MFMAs)
      if (kk + 1 < KS) {
        if (kk + 1 < KS1)
          a[rt] = *(const bf16x8*)&a1[(rt * KSA1 + kk + 1) * 512];
        else
          a[rt] = *(const bf16x8*)&a2[(rt * KSA2 + (kk + 1 - KS1)) * 512];
      }
    }
    __builtin_amdgcn_s_setprio(0);
#pragma unroll
    for (int ct = 0; ct < NT; ++ct)
      bcur[ct] = bnxt[ct];
  }
}

// Store acc (+bias, relu) into fragment-ordered H (KSH=8 stride).
template<int NT, bool RELU>
__device__ __forceinline__ void store_acc(
    const f32x4 (&acc)[4][NT], const float* bias,
    unsigned short* Out, int lane, int wid)
{
  const int l15 = lane & 15;
  const int l4  = lane >> 4;
  const int colbase = wid * (NT * 16);
#pragma unroll
  for (int ct = 0; ct < NT; ++ct) {
    const int c0 = colbase + ct * 16 + l4 * 4;
    const f32x4 bv = *(const f32x4*)&bias[c0];
    const int f  = c0 >> 5;
    const int li = l15 + 16 * ((c0 >> 3) & 3);
    const int e0 = c0 & 7;
#pragma unroll
    for (int rt = 0; rt < 4; ++rt) {
      float v0 = acc[rt][ct][0] + bv[0];
      float v1 = acc[rt][ct][1] + bv[1];
      float v2 = acc[rt][ct][2] + bv[2];
      float v3 = acc[rt][ct][3] + bv[3];
      if (RELU) {
        v0 = fmaxf(v0, 0.f); v1 = fmaxf(v1, 0.f);
        v2 = fmaxf(v2, 0.f); v3 = fmaxf(v3, 0.f);
      }
      uint2 u;
      u.x = (unsigned)f2bfu(v0) | ((unsigned)f2bfu(v1) << 16);
      u.y = (unsigned)f2bfu(v2) | ((unsigned)f2bfu(v3) << 16);
      *(uint2*)&Out[(rt * 8 + f) * 512 + li * 8 + e0] = u;
    }
  }
}

// L7 store + fused sigma partials (h7 . Wsig); fragment-ordered write.
__device__ __forceinline__ void store_acc_sigma(
    const f32x4 (&acc)[4][4], const float* bias,
    unsigned short* Out, float* Sb, int lane, int wid)
{
  const int l15 = lane & 15;
  const int l4  = lane >> 4;
  const int colbase = wid * 64;
  float ps[4] = {0.f, 0.f, 0.f, 0.f};
#pragma unroll
  for (int ct = 0; ct < 4; ++ct) {
    const int c0 = colbase + ct * 16 + l4 * 4;
    const f32x4 bv = *(const f32x4*)&bias[c0];
    const int f  = c0 >> 5;
    const int li = l15 + 16 * ((c0 >> 3) & 3);
    const int e0 = c0 & 7;
    const ushort4 wu = *(const ushort4*)&g_w[OFF_WSIG + c0];
    const float w0 = bfu2f(wu.x), w1 = bfu2f(wu.y), w2 = bfu2f(wu.z), w3 = bfu2f(wu.w);
#pragma unroll
    for (int rt = 0; rt < 4; ++rt) {
      float v0 = fmaxf(acc[rt][ct][0] + bv[0], 0.f);
      float v1 = fmaxf(acc[rt][ct][1] + bv[1], 0.f);
      float v2 = fmaxf(acc[rt][ct][2] + bv[2], 0.f);
      float v3 = fmaxf(acc[rt][ct][3] + bv[3], 0.f);
      uint2 u;
      u.x = (unsigned)f2bfu(v0) | ((unsigned)f2bfu(v1) << 16);
      u.y = (unsigned)f2bfu(v2) | ((unsigned)f2bfu(v3) << 16);
      *(uint2*)&Out[(rt * 8 + f) * 512 + li * 8 + e0] = u;
      ps[rt] += bfu2f(f2bfu(v0)) * w0 + bfu2f(f2bfu(v1)) * w1
              + bfu2f(f2bfu(v2)) * w2 + bfu2f(f2bfu(v3)) * w3;
    }
  }
#pragma unroll
  for (int rt = 0; rt < 4; ++rt) {
    ps[rt] += __shfl_xor(ps[rt], 16);
    ps[rt] += __shfl_xor(ps[rt], 32);
  }
  if (l4 == 0) {
#pragma unroll
    for (int rt = 0; rt < 4; ++rt)
      Sb[wid * 64 + rt * 16 + l15] = ps[rt];
  }
}

// L12 epilogue: rgb partials straight from acc2.
__device__ __forceinline__ void rgb_partial(
    const f32x4 (&acc)[4][2], const float* bias,
    float* Rb, int lane, int wid)
{
  const int l15 = lane & 15;
  const int l4  = lane >> 4;
  const int colbase = wid * 32;
  float pr[4][3] = {};
#pragma unroll
  for (int ct = 0; ct < 2; ++ct) {
    const int c0 = colbase + ct * 16 + l4 * 4;
    const f32x4 bv = *(const f32x4*)&bias[c0];
    float wf[3][4];
#pragma unroll
    for (int ch = 0; ch < 3; ++ch) {
      const ushort4 wu = *(const ushort4*)&g_w[OFF_WRGB + ch * 128 + c0];
      wf[ch][0] = bfu2f(wu.x); wf[ch][1] = bfu2f(wu.y);
      wf[ch][2] = bfu2f(wu.z); wf[ch][3] = bfu2f(wu.w);
    }
#pragma unroll
    for (int rt = 0; rt < 4; ++rt) {
      float v0 = fmaxf(acc[rt][ct][0] + bv[0], 0.f);
      float v1 = fmaxf(acc[rt][ct][1] + bv[1], 0.f);
      float v2 = fmaxf(acc[rt][ct][2] + bv[2], 0.f);
      float v3 = fmaxf(acc[rt][ct][3] + bv[3], 0.f);
#pragma unroll
      for (int ch = 0; ch < 3; ++ch)
        pr[rt][ch] += v0 * wf[ch][0] + v1 * wf[ch][1] + v2 * wf[ch][2] + v3 * wf[ch][3];
    }
  }
#pragma unroll
  for (int rt = 0; rt < 4; ++rt)
#pragma unroll
    for (int ch = 0; ch < 3; ++ch) {
      pr[rt][ch] += __shfl_xor(pr[rt][ch], 16);
      pr[rt][ch] += __shfl_xor(pr[rt][ch], 32);
    }
  if (l4 == 0) {
#pragma unroll
    for (int rt = 0; rt < 4; ++rt)
#pragma unroll
      for (int ch = 0; ch < 3; ++ch)
        Rb[((wid * 4 + rt) * 3 + ch) * 16 + l15] = pr[rt][ch];
  }
}

__launch_bounds__(256, 3)
__global__ void nerf_main(const float* __restrict__ x, const float* __restrict__ d,
    const float* b0, const float* b1, const float* b2, const float* b3,
    const float* b4, const float* b5, const float* b6, const float* b7,
    const float* bsig, const float* b8, const float* b9, const float* b10,
    const float* b11, const float* b12, const float* brgb,
    float* __restrict__ out)
{
  __shared__ __align__(16) unsigned short H[64 * 256];   // 32768 B, fragment-ordered KSH=8
  __shared__ __align__(16) unsigned short Xb[64 * 64];   // 8192 B, fragment-ordered KSX=2
  __shared__ __align__(16) unsigned short Db[64 * 32];   // 4096 B, fragment-ordered KSD=1
  __shared__ float Sb[256];                // 1024 B sigma partials
  __shared__ float Rb[768];                // 3072 B rgb partials
  // total 49152 B -> 3 blocks/CU

  const int tid = threadIdx.x;
  const int lane = tid & 63;
  const int wid = tid >> 6;
  const int rowbase = blockIdx.x * RTILE;

  // ---- stage x and d tiles (fp32 -> bf16, fragment-ordered writes) ----
  {
    const int r = tid >> 2;      // 0..63
    const int sub = tid & 3;
    const int rt = r >> 4;
    const int rl = r & 15;
    const float* xr = x + (size_t)(rowbase + r) * 63;
    for (int j = 0; j < 16; ++j) {
      const int c = sub + j * 4;        // 0..63
      const unsigned short v = (c < 63) ? f2bfu(xr[c]) : (unsigned short)0;
      Xb[(rt * 2 + (c >> 5)) * 512 + (rl + 16 * ((c >> 3) & 3)) * 8 + (c & 7)] = v;
    }
    const float* dr = d + (size_t)(rowbase + r) * 27;
    for (int j = 0; j < 8; ++j) {
      const int c = sub + j * 4;        // 0..31
      const unsigned short v = (c < 27) ? f2bfu(dr[c]) : (unsigned short)0;
      Db[rt * 512 + (rl + 16 * ((c >> 3) & 3)) * 8 + (c & 7)] = v;
    }
  }
  __syncthreads();

  f32x4 acc4[4][4];
  f32x4 acc2[4][2];

  // L0: reads Xb only -> write H directly (first writer)
  gemm_compute<2,2,0,0,2,4>(Xb, nullptr, g_w + OFF_W0, acc4, lane, wid);
  store_acc<4,true>(acc4, b0, H, lane, wid);
  __syncthreads();

#define BIG_LAYER(OFFW, BIAS) \
  gemm_compute<8,8,0,0,8,4>(H, nullptr, g_w + OFFW, acc4, lane, wid); \
  __syncthreads(); \
  store_acc<4,true>(acc4, BIAS, H, lane, wid); \
  __syncthreads();

  BIG_LAYER(OFF_W1, b1)
  BIG_LAYER(OFF_W2, b2)
  BIG_LAYER(OFF_W3, b3)
  BIG_LAYER(OFF_W4, b4)

  // L5: concat [h(256) | x(63)+pad] -> K=320
  gemm_compute<8,8,2,2,10,4>(H, Xb, g_w + OFF_W5, acc4, lane, wid);
  __syncthreads();
  store_acc<4,true>(acc4, b5, H, lane, wid);
  __syncthreads();

  BIG_LAYER(OFF_W6, b6)

  // L7 + fused sigma partials
  gemm_compute<8,8,0,0,8,4>(H, nullptr, g_w + OFF_W7, acc4, lane, wid);
  __syncthreads();
  store_acc_sigma(acc4, b7, H, Sb, lane, wid);
  __syncthreads();

  // finish sigma: 64 threads, Sb stable from here on
  if (tid < 64) {
    float s = Sb[tid] + Sb[64 + tid] + Sb[128 + tid] + Sb[192 + tid] + bsig[0];
    float sp = (s > 0.f) ? (s + log1pf(expf(-s))) : log1pf(expf(s));
    out[3 * NB + rowbase + tid] = sp;
  }

  // L8 (bottleneck, no relu)
  gemm_compute<8,8,0,0,8,4>(H, nullptr, g_w + OFF_W8, acc4, lane, wid);
  __syncthreads();
  store_acc<4,false>(acc4, b8, H, lane, wid);
  __syncthreads();

  // L9: concat [h8(256) | d(27)+pad] -> K=288, N=128 (d from Db)
  gemm_compute<8,8,1,1,9,2>(H, Db, g_w + OFF_W9, acc2, lane, wid);
  __syncthreads();
  store_acc<2,true>(acc2, b9, H, lane, wid);
  __syncthreads();

#define SMALL_LAYER(OFFW, BIAS) \
  gemm_compute<4,8,0,0,4,2>(H, nullptr, g_w + OFFW, acc2, lane, wid); \
  __syncthreads(); \
  store_acc<2,true>(acc2, BIAS, H, lane, wid); \
  __syncthreads();

  SMALL_LAYER(OFF_W10, b10)
  SMALL_LAYER(OFF_W11, b11)

  // L12 + fused rgb head: h12 never touches LDS
  gemm_compute<4,8,0,0,4,2>(H, nullptr, g_w + OFF_W12, acc2, lane, wid);
  rgb_partial(acc2, b12, Rb, lane, wid);
  __syncthreads();

  if (tid < 192) {
    const int r = tid / 3;
    const int ch = tid - r * 3;
    const int rt = r >> 4;
    const int l15r = r & 15;
    float s = brgb[ch];
#pragma unroll
    for (int w = 0; w < 4; ++w)
      s += Rb[((w * 4 + rt) * 3 + ch) * 16 + l15r];
    float val = 1.f / (1.f + expf(-s));
    out[(size_t)(rowbase + r) * 3 + ch] = val;
  }
}

extern "C" void kernel_launch(void* const* d_in, const int* in_sizes, int n_in,
                              void* d_out, int out_size, void* d_ws, size_t ws_size,
                              hipStream_t stream) {
  const float* x    = (const float*)d_in[0];
  const float* dd   = (const float*)d_in[1];
  const float* W0   = (const float*)d_in[2];
  const float* b0   = (const float*)d_in[3];
  const float* W1   = (const float*)d_in[4];
  const float* b1   = (const float*)d_in[5];
  const float* W2   = (const float*)d_in[6];
  const float* b2   = (const float*)d_in[7];
  const float* W3   = (const float*)d_in[8];
  const float* b3   = (const float*)d_in[9];
  const float* W4   = (const float*)d_in[10];
  const float* b4   = (const float*)d_in[11];
  const float* W5   = (const float*)d_in[12];
  const float* b5   = (const float*)d_in[13];
  const float* W6   = (const float*)d_in[14];
  const float* b6   = (const float*)d_in[15];
  const float* W7   = (const float*)d_in[16];
  const float* b7   = (const float*)d_in[17];
  const float* Wsig = (const float*)d_in[18];
  const float* bsig = (const float*)d_in[19];
  const float* W8   = (const float*)d_in[20];
  const float* b8   = (const float*)d_in[21];
  const float* W9   = (const float*)d_in[22];
  const float* b9   = (const float*)d_in[23];
  const float* W10  = (const float*)d_in[24];
  const float* b10  = (const float*)d_in[25];
  const float* W11  = (const float*)d_in[26];
  const float* b11  = (const float*)d_in[27];
  const float* W12  = (const float*)d_in[28];
  const float* b12  = (const float*)d_in[29];
  const float* Wrgb = (const float*)d_in[30];
  const float* brgb = (const float*)d_in[31];

  prep_kernel<<<(WTOTAL + 255) / 256, 256, 0, stream>>>(
      W0, W1, W2, W3, W4, W5, W6, W7, Wsig, W8, W9, W10, W11, W12, Wrgb);

  nerf_main<<<NB / RTILE, 256, 0, stream>>>(
      x, dd, b0, b1, b2, b3, b4, b5, b6, b7, bsig, b8, b9, b10, b11, b12, brgb,
      (float*)d_out);
}